// Round 1
// baseline (275.638 us; speedup 1.0000x reference)
//
#include <hip/hip_runtime.h>
#include <math.h>

#define NQ 10
#define DEPTH 6

// ---------------------------------------------------------------------------
// Kernel 1: precompute the 60 Rot(phi,theta,omega) 2x2 complex matrices.
// Rot = RZ(omega) RY(theta) RZ(phi) = [[ep*c, -conj(em)*s],[em*s, conj(ep)*c]]
// ep = exp(-0.5i(phi+omega)), em = exp(-0.5i(phi-omega))
// Layout in ws: gate (l*NQ+i) -> 8 floats: u00r,u00i,u01r,u01i,u10r,u10i,u11r,u11i
// ---------------------------------------------------------------------------
__global__ void prep_gates_kernel(const float* __restrict__ weights,
                                  float* __restrict__ gmat) {
    int idx = blockIdx.x * blockDim.x + threadIdx.x;
    if (idx >= DEPTH * NQ) return;
    float phi   = weights[idx * 3 + 0];
    float theta = weights[idx * 3 + 1];
    float omega = weights[idx * 3 + 2];
    float c = cosf(0.5f * theta), s = sinf(0.5f * theta);
    float ap = -0.5f * (phi + omega);
    float am = -0.5f * (phi - omega);
    float epr = cosf(ap), epi = sinf(ap);   // ep = epr + i*epi
    float emr = cosf(am), emi = sinf(am);   // em = emr + i*emi
    float* g = gmat + idx * 8;
    g[0] =  epr * c;  g[1] =  epi * c;    // u00 = ep*c
    g[2] = -emr * s;  g[3] =  emi * s;    // u01 = -conj(em)*s
    g[4] =  emr * s;  g[5] =  emi * s;    // u10 = em*s
    g[6] =  epr * c;  g[7] = -epi * c;    // u11 = conj(ep)*c
}

// ---------------------------------------------------------------------------
// State layout: one wave (64 lanes) holds one batch element's 1024-amp state.
// Amp index g in [0,1024): qubit q bit = (g>>q)&1.
//   bits 0..3  -> within-lane slot j in [0,16)   ("local" qubits)
//   bits 4..9  -> lane id                        ("lane" qubits)
// ---------------------------------------------------------------------------

__device__ __forceinline__ void apply_1q_local(
    float (&ar)[16], float (&ai)[16], int q,
    float u00r, float u00i, float u01r, float u01i,
    float u10r, float u10i, float u11r, float u11i) {
#pragma unroll
    for (int j = 0; j < 16; ++j) {
        if ((j >> q) & 1) continue;          // compile-time after unroll
        int j1 = j | (1 << q);
        float a0r = ar[j],  a0i = ai[j];
        float a1r = ar[j1], a1i = ai[j1];
        ar[j]  = u00r*a0r - u00i*a0i + u01r*a1r - u01i*a1i;
        ai[j]  = u00r*a0i + u00i*a0r + u01r*a1i + u01i*a1r;
        ar[j1] = u10r*a0r - u10i*a0i + u11r*a1r - u11i*a1i;
        ai[j1] = u10r*a0i + u10i*a0r + u11r*a1i + u11i*a1r;
    }
}

__device__ __forceinline__ void apply_1q_lane(
    float (&ar)[16], float (&ai)[16], int q, int lane,
    float u00r, float u00i, float u01r, float u01i,
    float u10r, float u10i, float u11r, float u11i) {
    int  m  = 1 << (q - 4);
    bool hi = (lane >> (q - 4)) & 1;
    // coefficient on my amp, coefficient on partner amp
    float car = hi ? u11r : u00r, cai = hi ? u11i : u00i;
    float cbr = hi ? u10r : u01r, cbi = hi ? u10i : u01i;
#pragma unroll
    for (int j = 0; j < 16; ++j) {
        float pr = __shfl_xor(ar[j], m, 64);
        float pi = __shfl_xor(ai[j], m, 64);
        float mr = ar[j], mi = ai[j];
        ar[j] = car*mr - cai*mi + cbr*pr - cbi*pi;
        ai[j] = car*mi + cai*mr + cbr*pi + cbi*pr;
    }
}

// CNOT(c,t): where control bit = 1, swap amplitudes along target bit t.
__device__ __forceinline__ void cnot_gate(
    float (&ar)[16], float (&ai)[16], int c, int t, int lane) {
    if (c < 4 && t < 4) {                   // both local: register permutation
#pragma unroll
        for (int j = 0; j < 16; ++j) {
            if (((j >> c) & 1) && !((j >> t) & 1)) {
                int j1 = j | (1 << t);
                float tr = ar[j]; ar[j] = ar[j1]; ar[j1] = tr;
                float ti = ai[j]; ai[j] = ai[j1]; ai[j1] = ti;
            }
        }
    } else if (c < 4) {                     // control local, target lane
        int m = 1 << (t - 4);
#pragma unroll
        for (int j = 0; j < 16; ++j) {
            if ((j >> c) & 1) {             // both partner lanes share this j-bit
                ar[j] = __shfl_xor(ar[j], m, 64);
                ai[j] = __shfl_xor(ai[j], m, 64);
            }
        }
    } else if (t < 4) {                     // control lane, target local
        bool cb = (lane >> (c - 4)) & 1;
#pragma unroll
        for (int j = 0; j < 16; ++j) {
            if (!((j >> t) & 1)) {
                int j1 = j | (1 << t);
                float lr = ar[j], li = ai[j], hr = ar[j1], hi2 = ai[j1];
                ar[j]  = cb ? hr : lr;  ai[j]  = cb ? hi2 : li;
                ar[j1] = cb ? lr : hr;  ai[j1] = cb ? li : hi2;
            }
        }
    } else {                                // both lane
        int  m  = 1 << (t - 4);
        bool cb = (lane >> (c - 4)) & 1;    // partner lane has same c-bit -> swap ok
#pragma unroll
        for (int j = 0; j < 16; ++j) {
            float pr = __shfl_xor(ar[j], m, 64);
            float pi = __shfl_xor(ai[j], m, 64);
            ar[j] = cb ? pr : ar[j];
            ai[j] = cb ? pi : ai[j];
        }
    }
}

template <int R>
__device__ __forceinline__ void cnot_ring(float (&ar)[16], float (&ai)[16], int lane) {
#pragma unroll
    for (int i = 0; i < NQ; ++i) cnot_gate(ar, ai, i, (i + R) % NQ, lane);
}

__device__ __forceinline__ float wave_sum(float v) {
#pragma unroll
    for (int m = 1; m < 64; m <<= 1) v += __shfl_xor(v, m, 64);
    return v;
}

// ---------------------------------------------------------------------------
// Main kernel: 4 waves/block, 1 wave per batch element.
// ---------------------------------------------------------------------------
__global__ __launch_bounds__(256) void vqc_kernel(
    const float* __restrict__ x,       // (B,1024)
    const float* __restrict__ Wproj,   // (10,1024)
    const float* __restrict__ gmat,    // (60,8) from prep
    const float* __restrict__ Wout,    // (10,10)
    const float* __restrict__ bout,    // (10,)
    float* __restrict__ out,           // (B,10)
    int B) {
    int lane = threadIdx.x & 63;
    int wid  = threadIdx.x >> 6;
    int b    = blockIdx.x * 4 + wid;
    if (b >= B) return;

    // ---- angles = tanh(x[b] . Wproj[q]) * pi/2 ----
    const float* xb = x + (size_t)b * 1024;
    float acc[NQ];
#pragma unroll
    for (int q = 0; q < NQ; ++q) acc[q] = 0.f;
#pragma unroll
    for (int k = 0; k < 16; ++k) {
        float xv = xb[k * 64 + lane];
#pragma unroll
        for (int q = 0; q < NQ; ++q)
            acc[q] = fmaf(xv, Wproj[q * 1024 + k * 64 + lane], acc[q]);
    }
#pragma unroll
    for (int q = 0; q < NQ; ++q) acc[q] = wave_sum(acc[q]);

    float cq[NQ], sq[NQ];
#pragma unroll
    for (int q = 0; q < NQ; ++q) {
        float ang = tanhf(acc[q]) * 1.57079632679489662f;
        cq[q] = cosf(0.5f * ang);
        sq[q] = sinf(0.5f * ang);
    }

    // ---- init product state (all RY gates folded in) ----
    float laneprod = 1.f;
#pragma unroll
    for (int q = 4; q < NQ; ++q)
        laneprod *= ((lane >> (q - 4)) & 1) ? sq[q] : cq[q];
    float ar[16], ai[16];
#pragma unroll
    for (int j = 0; j < 16; ++j) {
        float p = laneprod;
#pragma unroll
        for (int q = 0; q < 4; ++q) p *= ((j >> q) & 1) ? sq[q] : cq[q];
        ar[j] = p;
        ai[j] = 0.f;
    }

    // ---- entangling layers ----
    for (int l = 0; l < DEPTH; ++l) {       // runtime loop: bound code size
        const float* gl = gmat + l * (NQ * 8);
#pragma unroll
        for (int i = 0; i < NQ; ++i) {
            const float* g = gl + i * 8;
            float u00r = g[0], u00i = g[1], u01r = g[2], u01i = g[3];
            float u10r = g[4], u10i = g[5], u11r = g[6], u11i = g[7];
            if (i < 4)
                apply_1q_local(ar, ai, i, u00r,u00i,u01r,u01i,u10r,u10i,u11r,u11i);
            else
                apply_1q_lane(ar, ai, i, lane, u00r,u00i,u01r,u01i,u10r,u10i,u11r,u11i);
        }
        // r = (l % 9) + 1 = l+1 for DEPTH=6
        switch (l) {
            case 0: cnot_ring<1>(ar, ai, lane); break;
            case 1: cnot_ring<2>(ar, ai, lane); break;
            case 2: cnot_ring<3>(ar, ai, lane); break;
            case 3: cnot_ring<4>(ar, ai, lane); break;
            case 4: cnot_ring<5>(ar, ai, lane); break;
            default: cnot_ring<6>(ar, ai, lane); break;
        }
    }

    // ---- <Z_q> = sum_g p[g] * (1 - 2*bit_q(g)) ----
    float T = 0.f;
    float Sl[4] = {0.f, 0.f, 0.f, 0.f};
#pragma unroll
    for (int j = 0; j < 16; ++j) {
        float p = ar[j] * ar[j] + ai[j] * ai[j];
        T += p;
#pragma unroll
        for (int q = 0; q < 4; ++q) Sl[q] += ((j >> q) & 1) ? -p : p;
    }
    float Zq[NQ];
#pragma unroll
    for (int q = 0; q < 4; ++q) Zq[q] = Sl[q];
#pragma unroll
    for (int q = 4; q < NQ; ++q) Zq[q] = ((lane >> (q - 4)) & 1) ? -T : T;
#pragma unroll
    for (int q = 0; q < NQ; ++q) Zq[q] = wave_sum(Zq[q]);

    // ---- output head: out[b,c] = b_out[c] + sum_q Z_q * W_out[c,q] ----
    if (lane < NQ) {
        float o = bout[lane];
#pragma unroll
        for (int q = 0; q < NQ; ++q) o = fmaf(Zq[q], Wout[lane * NQ + q], o);
        out[(size_t)b * NQ + lane] = o;
    }
}

extern "C" void kernel_launch(void* const* d_in, const int* in_sizes, int n_in,
                              void* d_out, int out_size, void* d_ws, size_t ws_size,
                              hipStream_t stream) {
    const float* x       = (const float*)d_in[0];
    const float* Wproj   = (const float*)d_in[1];
    const float* weights = (const float*)d_in[2];
    const float* Wout    = (const float*)d_in[3];
    const float* bout    = (const float*)d_in[4];
    float* out  = (float*)d_out;
    float* gmat = (float*)d_ws;                 // 60*8 floats = 1920 B
    int B = in_sizes[0] / 1024;                 // 8192

    prep_gates_kernel<<<1, 64, 0, stream>>>(weights, gmat);
    vqc_kernel<<<(B + 3) / 4, 256, 0, stream>>>(x, Wproj, gmat, Wout, bout, out, B);
}